// Round 2
// baseline (223.071 us; speedup 1.0000x reference)
//
#include <hip/hip_runtime.h>
#include <math.h>

#define WSZ 11
#define HALO 5
#define TILE_W 64
#define TILE_H 16
#define IN_W (TILE_W + 2*HALO)   // 74
#define IN_H (TILE_H + 2*HALO)   // 26
#define IN_WP 76                 // padded LDS stride (16B-aligned rows)
#define IMG_H 512
#define IMG_W 512
#define NTX (IMG_W / TILE_W)     // 8
#define NTY (IMG_H / TILE_H)     // 32
#define NIMG 48                  // 16*3
#define NBLOCKS (NTX * NTY * NIMG)   // 12288
#define NPIX (16LL * 3 * 512 * 512)  // 12582912

#define C1F 0.0001f
#define C2F 0.0009f

__global__ __launch_bounds__(256)
void ssim_tile_kernel(const float* __restrict__ xg, const float* __restrict__ yg,
                      float* __restrict__ partials) {
    __shared__ __align__(16) float sx[IN_H][IN_WP];
    __shared__ __align__(16) float sy[IN_H][IN_WP];
    __shared__ __align__(16) float hbuf[5][IN_H][TILE_W];
    __shared__ float red[8];

    const int tid = threadIdx.x;
    const int img = blockIdx.z;
    const int tx0 = blockIdx.x * TILE_W - HALO;
    const int ty0 = blockIdx.y * TILE_H - HALO;
    const float* __restrict__ xi = xg + (size_t)img * (IMG_H * IMG_W);
    const float* __restrict__ yi = yg + (size_t)img * (IMG_H * IMG_W);

    // Gaussian weights (match np.float32 exp + normalize within rounding)
    float g[WSZ];
    {
        float s = 0.f;
        #pragma unroll
        for (int k = 0; k < WSZ; ++k) {
            float d = (float)(k - HALO);
            g[k] = expf(-(d * d) / 4.5f);
            s += g[k];
        }
        float inv = 1.f / s;
        #pragma unroll
        for (int k = 0; k < WSZ; ++k) g[k] *= inv;
    }

    // ---- Stage x, y tiles with halo (zero-padded at image borders) ----
    for (int idx = tid; idx < IN_H * IN_W; idx += 256) {
        int r = idx / IN_W;
        int c = idx - r * IN_W;
        int gr = ty0 + r, gc = tx0 + c;
        float xv = 0.f, yv = 0.f;
        if (gr >= 0 && gr < IMG_H && gc >= 0 && gc < IMG_W) {
            size_t o = (size_t)gr * IMG_W + gc;
            xv = xi[o];
            yv = yi[o];
        }
        sx[r][c] = xv;
        sy[r][c] = yv;
    }
    __syncthreads();

    // ---- Horizontal pass: 26 rows x 8 runs of 8 cols = 208 threads ----
    if (tid < IN_H * (TILE_W / 8)) {
        int row = tid >> 3;
        int rc = (tid & 7) * 8;
        float wx[18], wy[18];
        #pragma unroll
        for (int i = 0; i < 18; ++i) {
            wx[i] = sx[row][rc + i];
            wy[i] = sy[row][rc + i];
        }
        #pragma unroll
        for (int j = 0; j < 8; ++j) {
            float s1 = 0.f, s2 = 0.f, s11 = 0.f, s22 = 0.f, s12 = 0.f;
            #pragma unroll
            for (int k = 0; k < WSZ; ++k) {
                float a = wx[j + k], b = wy[j + k];
                float ga = g[k] * a, gb = g[k] * b;
                s1 += ga;
                s2 += gb;
                s11 = fmaf(ga, a, s11);
                s22 = fmaf(gb, b, s22);
                s12 = fmaf(ga, b, s12);
            }
            hbuf[0][row][rc + j] = s1;
            hbuf[1][row][rc + j] = s2;
            hbuf[2][row][rc + j] = s11;
            hbuf[3][row][rc + j] = s22;
            hbuf[4][row][rc + j] = s12;
        }
    }
    __syncthreads();

    // ---- Vertical pass: each thread = 1 col x 4 output rows ----
    const int col = tid & 63;
    const int r0 = (tid >> 6) << 2;   // 0,4,8,12

    float acc[5][4];
    #pragma unroll
    for (int a = 0; a < 5; ++a)
        #pragma unroll
        for (int j = 0; j < 4; ++j) acc[a][j] = 0.f;

    // Output rows r0+j (j=0..3) need hbuf rows r0+j .. r0+j+10 -> rr = 0..13 (14 rows)
    #pragma unroll
    for (int a = 0; a < 5; ++a) {
        #pragma unroll
        for (int rr = 0; rr < 14; ++rr) {
            float v = hbuf[a][r0 + rr][col];
            #pragma unroll
            for (int j = 0; j < 4; ++j) {
                int k = rr - j;
                if (k >= 0 && k < WSZ) acc[a][j] = fmaf(g[k], v, acc[a][j]);
            }
        }
    }

    float ssim_loc = 0.f, l1_loc = 0.f;
    #pragma unroll
    for (int j = 0; j < 4; ++j) {
        float m1 = acc[0][j], m2 = acc[1][j];
        float exx = acc[2][j], eyy = acc[3][j], exy = acc[4][j];
        float m1s = m1 * m1, m2s = m2 * m2, m12 = m1 * m2;
        float v1 = exx - m1s, v2 = eyy - m2s, v12 = exy - m12;
        float num = (2.f * m12 + C1F) * (2.f * v12 + C2F);
        float den = (m1s + m2s + C1F) * (v1 + v2 + C2F);
        ssim_loc += num / den;
        float a = sx[r0 + j + HALO][col + HALO];
        float b = sy[r0 + j + HALO][col + HALO];
        l1_loc += fabsf(a - b);
    }

    // ---- Block reduction ----
    #pragma unroll
    for (int off = 32; off > 0; off >>= 1) {
        ssim_loc += __shfl_down(ssim_loc, off);
        l1_loc += __shfl_down(l1_loc, off);
    }
    int wave = tid >> 6, lane = tid & 63;
    if (lane == 0) {
        red[wave] = ssim_loc;
        red[4 + wave] = l1_loc;
    }
    __syncthreads();
    if (tid == 0) {
        float ss = red[0] + red[1] + red[2] + red[3];
        float ll = red[4] + red[5] + red[6] + red[7];
        int bid = blockIdx.x + gridDim.x * (blockIdx.y + gridDim.y * blockIdx.z);
        partials[bid] = ss;
        partials[NBLOCKS + bid] = ll;
    }
}

__global__ __launch_bounds__(256)
void finalize_kernel(const float* __restrict__ partials, float* __restrict__ out) {
    __shared__ double rs[4], rl[4];
    const int tid = threadIdx.x;
    double ss = 0.0, ll = 0.0;
    for (int i = tid; i < NBLOCKS; i += 256) {
        ss += (double)partials[i];
        ll += (double)partials[NBLOCKS + i];
    }
    #pragma unroll
    for (int off = 32; off > 0; off >>= 1) {
        ss += __shfl_down(ss, off);
        ll += __shfl_down(ll, off);
    }
    int wave = tid >> 6, lane = tid & 63;
    if (lane == 0) { rs[wave] = ss; rl[wave] = ll; }
    __syncthreads();
    if (tid == 0) {
        double sst = rs[0] + rs[1] + rs[2] + rs[3];
        double llt = rl[0] + rl[1] + rl[2] + rl[3];
        double invn = 1.0 / (double)NPIX;
        out[0] = (float)(llt * invn + (1.0 - sst * invn));
    }
}

extern "C" void kernel_launch(void* const* d_in, const int* in_sizes, int n_in,
                              void* d_out, int out_size, void* d_ws, size_t ws_size,
                              hipStream_t stream) {
    const float* x = (const float*)d_in[0];   // outputs
    const float* y = (const float*)d_in[1];   // labels
    float* out = (float*)d_out;
    float* partials = (float*)d_ws;           // needs 2*NBLOCKS*4 = 98,304 B

    dim3 grid(NTX, NTY, NIMG);
    dim3 block(256);
    ssim_tile_kernel<<<grid, block, 0, stream>>>(x, y, partials);
    finalize_kernel<<<1, 256, 0, stream>>>(partials, out);
}

// Round 3
// 194.904 us; speedup vs baseline: 1.1445x; 1.1445x over previous
//
#include <hip/hip_runtime.h>
#include <math.h>

#define WSZ 11
#define HALO 5
#define TILE_W 64
#define TILE_H 16
#define IN_W 74                  // TILE_W + 2*HALO
#define IN_WP 75                 // odd LDS stride -> conflict-free lane patterns
#define IN_H 26                  // TILE_H + 2*HALO
#define IMG 512
#define NTX 8
#define NTY 32
#define NIMG 48
#define NBLOCKS (NTX * NTY * NIMG)   // 12288
#define NPIX (16LL * 3 * 512 * 512)  // 12582912

#define C1F 0.0001f
#define C2F 0.0009f

// Gaussian window (sigma=1.5, ws=11), normalized; derived in double precision.
// Max weight error ~1e-7, irrelevant vs 2.6e-2 threshold.
#define GW0 0.00102838f
#define GW1 0.00759877f
#define GW2 0.03600077f
#define GW3 0.10936069f
#define GW4 0.21300539f
#define GW5 0.26601172f

__global__ __launch_bounds__(256, 4)
void ssim_tile_kernel(const float* __restrict__ xg, const float* __restrict__ yg,
                      float* __restrict__ partials) {
    __shared__ float sx[IN_H][IN_WP];      // 7800 B
    __shared__ float sy[IN_H][IN_WP];      // 7800 B
    __shared__ float vbuf[5][TILE_H][IN_WP]; // 24000 B  (total 39632 B -> 4 blocks/CU)
    __shared__ float red[8];

    const float GW[WSZ] = {GW0, GW1, GW2, GW3, GW4, GW5, GW4, GW3, GW2, GW1, GW0};

    const int tid = threadIdx.x;
    const int img = blockIdx.z;
    const int tx0 = blockIdx.x * TILE_W - HALO;
    const int ty0 = blockIdx.y * TILE_H - HALO;
    const float* __restrict__ xi = xg + (size_t)img * (IMG * IMG);
    const float* __restrict__ yi = yg + (size_t)img * (IMG * IMG);

    // ---- Stage x, y tiles with halo (zero-pad at image borders) ----
    const bool interior = (tx0 >= 0) & (ty0 >= 0) & (tx0 + IN_W <= IMG) & (ty0 + IN_H <= IMG);
    if (interior) {
        for (int idx = tid; idx < IN_H * IN_W; idx += 256) {
            int r = idx / IN_W;
            int c = idx - r * IN_W;
            size_t o = (size_t)(ty0 + r) * IMG + (tx0 + c);
            sx[r][c] = xi[o];
            sy[r][c] = yi[o];
        }
    } else {
        for (int idx = tid; idx < IN_H * IN_W; idx += 256) {
            int r = idx / IN_W;
            int c = idx - r * IN_W;
            int gr = ty0 + r, gc = tx0 + c;
            float xv = 0.f, yv = 0.f;
            if (gr >= 0 && gr < IMG && gc >= 0 && gc < IMG) {
                size_t o = (size_t)gr * IMG + gc;
                xv = xi[o];
                yv = yi[o];
            }
            sx[r][c] = xv;
            sy[r][c] = yv;
        }
    }
    __syncthreads();

    // ---- Vertical pass first: 74 cols x 4 rowgroups(4 rows) = 296 units ----
    // Lanes on consecutive c -> stride-1 LDS reads/writes (conflict-free).
    for (int u = tid; u < 4 * IN_W; u += 256) {
        int rg = u / IN_W;          // 0..3
        int c  = u - rg * IN_W;     // 0..73
        int rbase = rg * 4;
        float a1[4]  = {0.f, 0.f, 0.f, 0.f};
        float a2[4]  = {0.f, 0.f, 0.f, 0.f};
        float a11[4] = {0.f, 0.f, 0.f, 0.f};
        float a22[4] = {0.f, 0.f, 0.f, 0.f};
        float a12[4] = {0.f, 0.f, 0.f, 0.f};
        #pragma unroll
        for (int rr = 0; rr < 14; ++rr) {   // rows rbase..rbase+13 feed outputs rbase+0..3
            float xv = sx[rbase + rr][c];
            float yv = sy[rbase + rr][c];
            float xx = xv * xv, yy = yv * yv, xy = xv * yv;
            #pragma unroll
            for (int j = 0; j < 4; ++j) {
                int k = rr - j;
                if (k >= 0 && k < WSZ) {
                    float w = GW[k];
                    a1[j]  = fmaf(w, xv, a1[j]);
                    a2[j]  = fmaf(w, yv, a2[j]);
                    a11[j] = fmaf(w, xx, a11[j]);
                    a22[j] = fmaf(w, yy, a22[j]);
                    a12[j] = fmaf(w, xy, a12[j]);
                }
            }
        }
        #pragma unroll
        for (int j = 0; j < 4; ++j) {
            vbuf[0][rbase + j][c] = a1[j];
            vbuf[1][rbase + j][c] = a2[j];
            vbuf[2][rbase + j][c] = a11[j];
            vbuf[3][rbase + j][c] = a22[j];
            vbuf[4][rbase + j][c] = a12[j];
        }
    }
    __syncthreads();

    // ---- Horizontal pass: 16 rows x 16 runs of 4 cols = 256 units (full util) ----
    // Lane address stride 75 (odd) -> <=2-way bank aliasing (free).
    const int row = tid & 15;
    const int rc  = (tid >> 4) << 2;   // 0,4,...,60

    float m1[4], m2[4], e11[4], e22[4], e12[4];
#define HCONV(DST, A)                                              \
    {                                                              \
        float w[14];                                               \
        _Pragma("unroll")                                          \
        for (int i = 0; i < 14; ++i) w[i] = vbuf[A][row][rc + i];  \
        _Pragma("unroll")                                          \
        for (int j = 0; j < 4; ++j) {                              \
            float s = 0.f;                                         \
            _Pragma("unroll")                                      \
            for (int k = 0; k < WSZ; ++k) s = fmaf(GW[k], w[j + k], s); \
            DST[j] = s;                                            \
        }                                                          \
    }
    HCONV(m1, 0)
    HCONV(m2, 1)
    HCONV(e11, 2)
    HCONV(e22, 3)
    HCONV(e12, 4)
#undef HCONV

    // ---- Per-pixel SSIM + L1 ----
    float ssim_loc = 0.f, l1_loc = 0.f;
    #pragma unroll
    for (int j = 0; j < 4; ++j) {
        float mu1 = m1[j], mu2 = m2[j];
        float m1s = mu1 * mu1, m2s = mu2 * mu2, m12 = mu1 * mu2;
        float v1 = e11[j] - m1s, v2 = e22[j] - m2s, v12 = e12[j] - m12;
        float num = (2.f * m12 + C1F) * (2.f * v12 + C2F);
        float den = (m1s + m2s + C1F) * (v1 + v2 + C2F);
        ssim_loc += num / den;
        float xa = sx[row + HALO][rc + j + HALO];
        float yb = sy[row + HALO][rc + j + HALO];
        l1_loc += fabsf(xa - yb);
    }

    // ---- Block reduction ----
    #pragma unroll
    for (int off = 32; off > 0; off >>= 1) {
        ssim_loc += __shfl_down(ssim_loc, off);
        l1_loc   += __shfl_down(l1_loc, off);
    }
    int wave = tid >> 6, lane = tid & 63;
    if (lane == 0) {
        red[wave] = ssim_loc;
        red[4 + wave] = l1_loc;
    }
    __syncthreads();
    if (tid == 0) {
        float ss = red[0] + red[1] + red[2] + red[3];
        float ll = red[4] + red[5] + red[6] + red[7];
        int bid = blockIdx.x + gridDim.x * (blockIdx.y + gridDim.y * blockIdx.z);
        partials[bid] = ss;
        partials[NBLOCKS + bid] = ll;
    }
}

__global__ __launch_bounds__(1024)
void finalize_kernel(const float* __restrict__ partials, float* __restrict__ out) {
    __shared__ double rs[16], rl[16];
    const int tid = threadIdx.x;
    double ss = 0.0, ll = 0.0;
    for (int i = tid; i < NBLOCKS; i += 1024) {
        ss += (double)partials[i];
        ll += (double)partials[NBLOCKS + i];
    }
    #pragma unroll
    for (int off = 32; off > 0; off >>= 1) {
        ss += __shfl_down(ss, off);
        ll += __shfl_down(ll, off);
    }
    int wave = tid >> 6, lane = tid & 63;
    if (lane == 0) { rs[wave] = ss; rl[wave] = ll; }
    __syncthreads();
    if (tid == 0) {
        double sst = 0.0, llt = 0.0;
        #pragma unroll
        for (int w = 0; w < 16; ++w) { sst += rs[w]; llt += rl[w]; }
        double invn = 1.0 / (double)NPIX;
        out[0] = (float)(llt * invn + (1.0 - sst * invn));
    }
}

extern "C" void kernel_launch(void* const* d_in, const int* in_sizes, int n_in,
                              void* d_out, int out_size, void* d_ws, size_t ws_size,
                              hipStream_t stream) {
    const float* x = (const float*)d_in[0];   // outputs
    const float* y = (const float*)d_in[1];   // labels
    float* out = (float*)d_out;
    float* partials = (float*)d_ws;           // 2*NBLOCKS*4 = 98,304 B

    dim3 grid(NTX, NTY, NIMG);
    ssim_tile_kernel<<<grid, dim3(256), 0, stream>>>(x, y, partials);
    finalize_kernel<<<1, dim3(1024), 0, stream>>>(partials, out);
}